// Round 15
// baseline (596.769 us; speedup 1.0000x reference)
//
#include <hip/hip_runtime.h>
#include <math.h>

#define Bn 16
#define Tn 16384
#define Fn 32
#define Cn 64
#define Ln 10
#define ST 76   // LDS tile row stride (elements): 152B -> conflict-free patterns

typedef _Float16 v8h  __attribute__((ext_vector_type(8)));
typedef _Float16 v4h  __attribute__((ext_vector_type(4)));
typedef float    v16f __attribute__((ext_vector_type(16)));
typedef float    v4f  __attribute__((ext_vector_type(4)));

// ---------------------------------------------------------------------------
// k_prep: pack weights fp32 -> fp16 in PER-LANE FRAGMENT ORDER so the layer
// kernels' A-operand loads are fully coalesced (16B/lane, 1KB/wave bursts).
// wfgP[l][chunk][lane][8]:  chunk = ((tap*4 + kc)*2 + fg)*2 + ch32
// rsP [l][chunk][lane][8]:  chunk = (kc*2 + rsi)*2 + ch32
// ---------------------------------------------------------------------------
__global__ __launch_bounds__(256) void k_prep(const float* __restrict__ fw,
                                              const float* __restrict__ gw,
                                              const float* __restrict__ rw,
                                              const float* __restrict__ sw,
                                              _Float16* __restrict__ wfgP,
                                              _Float16* __restrict__ rsP)
{
    int gid = blockIdx.x * 256 + threadIdx.x;
    if (gid < Ln * 24576) {
        int l      = gid / 24576;
        int rem    = gid % 24576;
        int chunk  = rem >> 9;
        int within = rem & 511;
        int lane   = within >> 3, j = within & 7;
        int ch32 = chunk & 1;
        int fg   = (chunk >> 1) & 1;
        int kc   = (chunk >> 2) & 3;
        int tap  = chunk >> 4;
        int co = ch32 * 32 + (lane & 31);
        int ci = kc * 16 + (lane >> 5) * 8 + j;
        const float* wsrc = fg ? gw : fw;
        wfgP[gid] = (_Float16)wsrc[((l * 64 + co) * 64 + ci) * 3 + tap];
    }
    int gid2 = gid - Ln * 24576;
    if (gid2 >= 0 && gid2 < Ln * 8192) {
        int l      = gid2 / 8192;
        int rem    = gid2 % 8192;
        int chunk  = rem >> 9;
        int within = rem & 511;
        int lane   = within >> 3, j = within & 7;
        int ch32 = chunk & 1;
        int rsi  = (chunk >> 1) & 1;
        int kc   = chunk >> 2;
        int co = ch32 * 32 + (lane & 31);
        int ci = kc * 16 + (lane >> 5) * 8 + j;
        const float* wsrc = rsi ? sw : rw;
        rsP[gid2] = (_Float16)wsrc[(l * 64 + co) * 64 + ci];
    }
}

// ---------------------------------------------------------------------------
// XCD-aware block swizzle: same t-slice -> same XCD in every kernel/layer.
// ---------------------------------------------------------------------------
__device__ __forceinline__ int xcd_swizzle(int bx, int nblk)
{
    return (bx & 7) * (nblk >> 3) + (bx >> 3);
}

// ---------------------------------------------------------------------------
// k_input: h[b][t][c] = fp16( sum_f w_in[c][f] * x[b][t][f] + b_in[c] )
// ---------------------------------------------------------------------------
__global__ __launch_bounds__(256) void k_input(const float* __restrict__ x,
                                               const float* __restrict__ w_in,
                                               const float* __restrict__ b_in,
                                               _Float16* __restrict__ h)
{
    __shared__ _Float16 HT[256 * 64];   // 32KB
    const int tid = threadIdx.x;
    const int blk = xcd_swizzle(blockIdx.x, Tn / 256);
    const int t0  = blk * 256;
    const int t   = t0 + tid;
    const int bb  = blockIdx.y;
    const float* xp = x + ((size_t)bb * Tn + t) * Fn;
    float xv[32];
    #pragma unroll
    for (int i = 0; i < 8; ++i) {
        v4f v = *(const v4f*)&xp[i * 4];
        xv[i*4+0] = v[0]; xv[i*4+1] = v[1]; xv[i*4+2] = v[2]; xv[i*4+3] = v[3];
    }
    #pragma unroll
    for (int c8 = 0; c8 < 8; ++c8) {
        v8h o;
        #pragma unroll
        for (int j = 0; j < 8; ++j) {
            int c = c8 * 8 + j;                 // loop-uniform -> s_loads
            float a = b_in[c];
            #pragma unroll
            for (int f = 0; f < 32; ++f) a = fmaf(w_in[c * 32 + f], xv[f], a);
            o[j] = (_Float16)a;
        }
        const int p = (c8 + tid) & 7;           // bank-rotate chunk slot
        *(v8h*)&HT[tid * 64 + p * 8] = o;
    }
    __syncthreads();
    _Float16* hp = h + ((size_t)bb * Tn + t0) * 64;
    #pragma unroll
    for (int it = 0; it < 8; ++it) {
        const int g  = it * 256 + tid;
        const int tl = g >> 3, c8 = g & 7;
        const int p  = (c8 + tl) & 7;
        *(v8h*)&hp[g * 8] = *(const v8h*)&HT[tl * 64 + p * 8];
    }
}

// ---------------------------------------------------------------------------
// k_pair: TWO fused layers (l, l+1), d = dil, d' = 2*dil, dil <= 16.
// h_mid never touches HBM; one skip RMW for both layers.  Saves ~96MB HBM
// per pair vs two k_layer dispatches (R13/R14 evidence: dur tracks bytes at
// ~2.1-2.5 TB/s delivered; structure changes alone are neutral).
//   UB: staged hin window [t0-96, t0+64)  (160 rows; 6d <= 96)
//   HB: h_mid [t0-64, t0+64)             (128 rows; 4d <= 64)
//   act overlays its h_mid chunk (2 barriers/chunk); act_{l+1}, hout tile
//   and skip tile overlay dead UB rows.
// LDS 43776B -> 3 blocks/CU.  Only cross-phase register state: accSl (16).
// Block 256 = 4 waves; out tile 64co x 64t; wave quarter 32co x 32t.
// mfma_f32_32x32x16_f16: A[m=lane&31][k=(lane>>5)*8+j], B[k][n=lane&31],
// D: col(n)=lane&31, row(m)=(reg&3)+8*(reg>>2)+4*(lane>>5).
// ---------------------------------------------------------------------------
__global__ __launch_bounds__(256, 3) void k_pair(
    const _Float16* __restrict__ hin, _Float16* __restrict__ hout,
    _Float16* __restrict__ skip,
    const _Float16* __restrict__ wfgA, const _Float16* __restrict__ rsA,
    const _Float16* __restrict__ wfgB, const _Float16* __restrict__ rsB,
    const float* __restrict__ fbA, const float* __restrict__ gbA,
    const float* __restrict__ rbA, const float* __restrict__ sbA,
    const float* __restrict__ fbB, const float* __restrict__ gbB,
    const float* __restrict__ rbB, const float* __restrict__ sbB,
    const int dil, const float skip_scale)
{
    __shared__ _Float16 UB[160 * ST];   // 24320B
    __shared__ _Float16 HB[128 * ST];   // 19456B

    const int tid  = threadIdx.x;
    const int lane = tid & 63;
    const int wv   = tid >> 6;
    const int ch32 = wv & 1;
    const int ch   = ch32 * 32;
    const int tw   = (wv >> 1) * 32;
    const int hl   = lane >> 5;
    const int ln31 = lane & 31;
    const int bb   = blockIdx.y;
    const int t0   = xcd_swizzle(blockIdx.x, Tn / 64) * 64;
    const size_t hbase = (size_t)bb * Tn * 64;

    v8h zero8;
    #pragma unroll
    for (int j = 0; j < 8; ++j) zero8[j] = (_Float16)0.f;

    const int s_tl = tid >> 3;              // 0..31
    const int s_c  = (tid & 7) * 8;

#define WOFF(TAP, KC, FG) (((((TAP) * 4 + (KC)) * 2 + (FG)) * 2 + ch32) * 512 + lane * 8)
#define RSOFF(KC, RSI)    ((((KC) * 2 + (RSI)) * 2 + ch32) * 512 + lane * 8)

    // ---- stage UB: 160 rows <-> t in [t0-96, t0+64)
    #pragma unroll
    for (int it = 0; it < 5; ++it) {
        int row = s_tl + it * 32;
        int tg  = t0 - 96 + row;
        v8h v = zero8;
        if (tg >= 0) v = *(const v8h*)&hin[hbase + (size_t)tg * 64 + s_c];
        *(v8h*)&UB[row * ST + s_c] = v;
    }
    __syncthreads();                        // B0: UB ready

    v16f accSl;                             // layer-l skip stash (chunk 1)

    // ---- mid layer (layer l): h_mid rows [0,128) <-> t in [t0-64, t0+64)
    #pragma unroll
    for (int c = 0; c < 2; ++c) {
        const int mrow = c * 64 + tw + ln31;          // h_mid row of this lane
        v16f accF, accG;
        #pragma unroll
        for (int q = 0; q < 4; ++q) {
            v4f fv = *(const v4f*)&fbA[ch + 8 * q + 4 * hl];
            v4f gv = *(const v4f*)&gbA[ch + 8 * q + 4 * hl];
            #pragma unroll
            for (int r = 0; r < 4; ++r) { accF[q*4+r] = fv[r]; accG[q*4+r] = gv[r]; }
        }
        #pragma unroll
        for (int tap = 0; tap < 3; ++tap) {
            const int ur = 32 + c * 64 + tw - (2 - tap) * dil;   // UB base row
            #pragma unroll
            for (int kc = 0; kc < 4; ++kc) {
                const int kof = kc * 16 + hl * 8;
                v8h aF = *(const v8h*)&wfgA[WOFF(tap, kc, 0)];
                v8h aG = *(const v8h*)&wfgA[WOFF(tap, kc, 1)];
                v8h b0 = *(const v8h*)&UB[(ur + ln31) * ST + kof];
                accF = __builtin_amdgcn_mfma_f32_32x32x16_f16(aF, b0, accF, 0, 0, 0);
                accG = __builtin_amdgcn_mfma_f32_32x32x16_f16(aG, b0, accG, 0, 0, 0);
            }
        }
        // act -> HB chunk rows (overlay: h_mid written to same cells later)
        #pragma unroll
        for (int q = 0; q < 4; ++q) {
            v4h av;
            #pragma unroll
            for (int r = 0; r < 4; ++r) {
                float f = accF[q * 4 + r];
                float g = accG[q * 4 + r];
                float A = __expf(2.f * f);
                float B = __expf(-g);
                float tA = A + 1.f;
                float den = fmaf(tA, B, tA);
                av[r] = (_Float16)((A - 1.f) * __builtin_amdgcn_rcpf(den));
            }
            *(v4h*)&HB[mrow * ST + ch + 8 * q + 4 * hl] = av;
        }
        __syncthreads();                    // B1c: act visible (both c-halves)

        v16f accR, accS;
        #pragma unroll
        for (int q = 0; q < 4; ++q) {
            v4f rv = *(const v4f*)&rbA[ch + 8 * q + 4 * hl];
            v4f sv = *(const v4f*)&sbA[ch + 8 * q + 4 * hl];
            #pragma unroll
            for (int r = 0; r < 4; ++r) { accR[q*4+r] = rv[r]; accS[q*4+r] = sv[r]; }
        }
        #pragma unroll
        for (int kc = 0; kc < 4; ++kc) {
            const int kof = kc * 16 + hl * 8;
            v8h aR = *(const v8h*)&rsA[RSOFF(kc, 0)];
            v8h b0 = *(const v8h*)&HB[mrow * ST + kof];
            accR = __builtin_amdgcn_mfma_f32_32x32x16_f16(aR, b0, accR, 0, 0, 0);
            if (c == 1) {
                v8h aS = *(const v8h*)&rsA[RSOFF(kc, 1)];
                accS = __builtin_amdgcn_mfma_f32_32x32x16_f16(aS, b0, accS, 0, 0, 0);
            }
        }
        __syncthreads();                    // B2c: all act reads done

        // h_mid = (hin + R)*0.7071 (zero for t<0) -> HB same cells
        const int tglob = t0 - 64 + c * 64 + tw + ln31;
        #pragma unroll
        for (int q = 0; q < 4; ++q) {
            v4h hv = *(const v4h*)&UB[(32 + c * 64 + tw + ln31) * ST + ch + 8 * q + 4 * hl];
            v4h hn;
            #pragma unroll
            for (int r = 0; r < 4; ++r)
                hn[r] = (tglob >= 0)
                      ? (_Float16)(((float)hv[r] + accR[q * 4 + r]) * 0.7071f)
                      : (_Float16)0.f;
            *(v4h*)&HB[mrow * ST + ch + 8 * q + 4 * hl] = hn;
        }
        if (c == 1) accSl = accS;
    }
    __syncthreads();                        // B3: h_mid complete; UB dead

    // ---- layer l+1: out tile [t0, t0+64), taps into HB at {0, 2d, 4d}
    {
        v16f accF, accG;
        #pragma unroll
        for (int q = 0; q < 4; ++q) {
            v4f fv = *(const v4f*)&fbB[ch + 8 * q + 4 * hl];
            v4f gv = *(const v4f*)&gbB[ch + 8 * q + 4 * hl];
            #pragma unroll
            for (int r = 0; r < 4; ++r) { accF[q*4+r] = fv[r]; accG[q*4+r] = gv[r]; }
        }
        #pragma unroll
        for (int tap = 0; tap < 3; ++tap) {
            const int hr = 64 + tw - (2 - tap) * 2 * dil;        // HB base row
            #pragma unroll
            for (int kc = 0; kc < 4; ++kc) {
                const int kof = kc * 16 + hl * 8;
                v8h aF = *(const v8h*)&wfgB[WOFF(tap, kc, 0)];
                v8h aG = *(const v8h*)&wfgB[WOFF(tap, kc, 1)];
                v8h b0 = *(const v8h*)&HB[(hr + ln31) * ST + kof];
                accF = __builtin_amdgcn_mfma_f32_32x32x16_f16(aF, b0, accF, 0, 0, 0);
                accG = __builtin_amdgcn_mfma_f32_32x32x16_f16(aG, b0, accG, 0, 0, 0);
            }
        }
        // act_{l+1} -> UB rows [0,64)
        #pragma unroll
        for (int q = 0; q < 4; ++q) {
            v4h av;
            #pragma unroll
            for (int r = 0; r < 4; ++r) {
                float f = accF[q * 4 + r];
                float g = accG[q * 4 + r];
                float A = __expf(2.f * f);
                float B = __expf(-g);
                float tA = A + 1.f;
                float den = fmaf(tA, B, tA);
                av[r] = (_Float16)((A - 1.f) * __builtin_amdgcn_rcpf(den));
            }
            *(v4h*)&UB[(tw + ln31) * ST + ch + 8 * q + 4 * hl] = av;
        }
        __syncthreads();                    // B4: act visible

        v16f accR, accS;
        #pragma unroll
        for (int q = 0; q < 4; ++q) {
            v4f rv = *(const v4f*)&rbB[ch + 8 * q + 4 * hl];
            v4f sv = *(const v4f*)&sbB[ch + 8 * q + 4 * hl];
            #pragma unroll
            for (int r = 0; r < 4; ++r) { accR[q*4+r] = rv[r]; accS[q*4+r] = sv[r]; }
        }
        #pragma unroll
        for (int kc = 0; kc < 4; ++kc) {
            const int kof = kc * 16 + hl * 8;
            v8h aR = *(const v8h*)&rsB[RSOFF(kc, 0)];
            v8h aS = *(const v8h*)&rsB[RSOFF(kc, 1)];
            v8h b0 = *(const v8h*)&UB[(tw + ln31) * ST + kof];
            accR = __builtin_amdgcn_mfma_f32_32x32x16_f16(aR, b0, accR, 0, 0, 0);
            accS = __builtin_amdgcn_mfma_f32_32x32x16_f16(aS, b0, accS, 0, 0, 0);
        }
        // h_out scatter -> UB rows [64,128): (h_mid + R)*0.7071
        #pragma unroll
        for (int q = 0; q < 4; ++q) {
            v4h hv = *(const v4h*)&HB[(64 + tw + ln31) * ST + ch + 8 * q + 4 * hl];
            v4h hn;
            #pragma unroll
            for (int r = 0; r < 4; ++r)
                hn[r] = (_Float16)(((float)hv[r] + accR[q * 4 + r]) * 0.7071f);
            *(v4h*)&UB[(64 + tw + ln31) * ST + ch + 8 * q + 4 * hl] = hn;
        }
        __syncthreads();                    // B5: act reads done + hout tile ready

        // skip tile -> UB rows [0,64): S_l + S_{l+1} (biases included in accs)
        #pragma unroll
        for (int q = 0; q < 4; ++q) {
            v4h sn;
            #pragma unroll
            for (int r = 0; r < 4; ++r)
                sn[r] = (_Float16)(accS[q * 4 + r] + accSl[q * 4 + r]);
            *(v4h*)&UB[(tw + ln31) * ST + ch + 8 * q + 4 * hl] = sn;
        }
        // hout coalesced store from UB rows [64,128)
        #pragma unroll
        for (int it = 0; it < 2; ++it) {
            int tl = s_tl + it * 32;
            *(v8h*)&hout[hbase + (size_t)(t0 + tl) * 64 + s_c] =
                *(const v8h*)&UB[(64 + tl) * ST + s_c];
        }
        __syncthreads();                    // B6: skip tile complete

        // skip coalesced RMW (scale==0 on the first pair: no load of poison)
        #pragma unroll
        for (int it = 0; it < 2; ++it) {
            int tl = s_tl + it * 32;
            const size_t base = hbase + (size_t)(t0 + tl) * 64 + s_c;
            v8h pv = *(const v8h*)&UB[tl * ST + s_c];
            v8h sn;
            if (skip_scale != 0.f) {
                v8h sk = *(const v8h*)&skip[base];
                #pragma unroll
                for (int r = 0; r < 8; ++r)
                    sn[r] = (_Float16)((float)sk[r] * skip_scale + (float)pv[r]);
            } else {
                sn = pv;
            }
            *(v8h*)&skip[base] = sn;
        }
    }
#undef WOFF
#undef RSOFF
}

// ---------------------------------------------------------------------------
// k_layer: single layer, d > 32 (tap windows disjoint) — R13 structure.
// write_h=0 skips the dead hout store on the final layer.
// ---------------------------------------------------------------------------
__global__ __launch_bounds__(256, 4) void k_layer(
    const _Float16* __restrict__ hin, _Float16* __restrict__ hout,
    _Float16* __restrict__ skip,
    const _Float16* __restrict__ wfg, const _Float16* __restrict__ rs,
    const float* __restrict__ fb, const float* __restrict__ gb,
    const float* __restrict__ rb, const float* __restrict__ sb,
    const int dil, const int write_h)
{
    __shared__ _Float16 P0[64 * ST];    // 9.7KB
    __shared__ _Float16 P1[64 * ST];    // 9.7KB

    const int tid  = threadIdx.x;
    const int lane = tid & 63;
    const int wv   = tid >> 6;
    const int ch32 = wv & 1;
    const int ch   = ch32 * 32;
    const int tw   = (wv >> 1) * 32;
    const int hl   = lane >> 5;
    const int ln31 = lane & 31;
    const int bb   = blockIdx.y;
    const int t0   = xcd_swizzle(blockIdx.x, Tn / 64) * 64;
    const size_t hbase = (size_t)bb * Tn * 64;

    v8h zero8;
    #pragma unroll
    for (int j = 0; j < 8; ++j) zero8[j] = (_Float16)0.f;

    const int s_tl = tid >> 3;
    const int s_c  = (tid & 7) * 8;

#define STAGE(DST, OFF) do {                                                  \
    _Pragma("unroll")                                                         \
    for (int it = 0; it < 2; ++it) {                                          \
        int tl = s_tl + it * 32;                                              \
        int tg = t0 + tl - (OFF);                                             \
        v8h v = zero8;                                                        \
        if (tg >= 0) v = *(const v8h*)&hin[hbase + (size_t)tg * 64 + s_c];    \
        *(v8h*)&(DST)[tl * ST + s_c] = v;                                     \
    } } while (0)

#define WOFF(TAP, KC, FG) (((((TAP) * 4 + (KC)) * 2 + (FG)) * 2 + ch32) * 512 + lane * 8)
#define RSOFF(KC, RSI)    ((((KC) * 2 + (RSI)) * 2 + ch32) * 512 + lane * 8)

#define MFMA_TAP(SRC, TAP) do {                                               \
    _Pragma("unroll")                                                         \
    for (int kc = 0; kc < 4; ++kc) {                                          \
        const int kof = kc * 16 + hl * 8;                                     \
        v8h aF = *(const v8h*)&wfg[WOFF(TAP, kc, 0)];                         \
        v8h aG = *(const v8h*)&wfg[WOFF(TAP, kc, 1)];                         \
        v8h b0 = *(const v8h*)&(SRC)[(tw + ln31) * ST + kof];                 \
        accF = __builtin_amdgcn_mfma_f32_32x32x16_f16(aF, b0, accF, 0, 0, 0); \
        accG = __builtin_amdgcn_mfma_f32_32x32x16_f16(aG, b0, accG, 0, 0, 0); \
    } } while (0)

    v16f accF, accG;
    #pragma unroll
    for (int q = 0; q < 4; ++q) {
        v4f fv = *(const v4f*)&fb[ch + 8 * q + 4 * hl];
        v4f gv = *(const v4f*)&gb[ch + 8 * q + 4 * hl];
        #pragma unroll
        for (int r = 0; r < 4; ++r) { accF[q*4+r] = fv[r]; accG[q*4+r] = gv[r]; }
    }

    STAGE(P0, 2 * dil);
    __syncthreads();                        // S1
    STAGE(P1, dil);
    MFMA_TAP(P0, 0);
    __syncthreads();                        // S2
    STAGE(P0, 0);
    MFMA_TAP(P1, 1);
    __syncthreads();                        // S3
    MFMA_TAP(P0, 2);                        // P0 holds hin[t]

    #pragma unroll
    for (int q = 0; q < 4; ++q) {
        v4h av;
        #pragma unroll
        for (int r = 0; r < 4; ++r) {
            float f = accF[q * 4 + r];
            float g = accG[q * 4 + r];
            float A = __expf(2.f * f);
            float B = __expf(-g);
            float tA = A + 1.f;
            float den = fmaf(tA, B, tA);
            av[r] = (_Float16)((A - 1.f) * __builtin_amdgcn_rcpf(den));
        }
        *(v4h*)&P1[(tw + ln31) * ST + ch + 8 * q + 4 * hl] = av;
    }
    __syncthreads();                        // S4

    v16f accR, accS;
    #pragma unroll
    for (int q = 0; q < 4; ++q) {
        v4f rv = *(const v4f*)&rb[ch + 8 * q + 4 * hl];
        v4f sv = *(const v4f*)&sb[ch + 8 * q + 4 * hl];
        #pragma unroll
        for (int r = 0; r < 4; ++r) { accR[q*4+r] = rv[r]; accS[q*4+r] = sv[r]; }
    }
    #pragma unroll
    for (int kc = 0; kc < 4; ++kc) {
        const int kof = kc * 16 + hl * 8;
        v8h aR = *(const v8h*)&rs[RSOFF(kc, 0)];
        v8h aS = *(const v8h*)&rs[RSOFF(kc, 1)];
        v8h b0 = *(const v8h*)&P1[(tw + ln31) * ST + kof];
        accR = __builtin_amdgcn_mfma_f32_32x32x16_f16(aR, b0, accR, 0, 0, 0);
        accS = __builtin_amdgcn_mfma_f32_32x32x16_f16(aS, b0, accS, 0, 0, 0);
    }

    if (write_h) {
        #pragma unroll
        for (int q = 0; q < 4; ++q) {
            _Float16* cell = &P0[(tw + ln31) * ST + ch + 8 * q + 4 * hl];
            v4h hv = *(const v4h*)cell;
            v4h hn;
            #pragma unroll
            for (int r = 0; r < 4; ++r)
                hn[r] = (_Float16)(((float)hv[r] + accR[q * 4 + r]) * 0.7071f);
            *(v4h*)cell = hn;
        }
    }
    __syncthreads();                        // S5

    #pragma unroll
    for (int q = 0; q < 4; ++q) {
        v4h sn;
        #pragma unroll
        for (int r = 0; r < 4; ++r)
            sn[r] = (_Float16)accS[q * 4 + r];
        *(v4h*)&P1[(tw + ln31) * ST + ch + 8 * q + 4 * hl] = sn;
    }
    if (write_h) {
        #pragma unroll
        for (int it = 0; it < 2; ++it) {
            int tl = s_tl + it * 32;
            *(v8h*)&hout[hbase + (size_t)(t0 + tl) * 64 + s_c] = *(const v8h*)&P0[tl * ST + s_c];
        }
    }
    __syncthreads();                        // S6

    #pragma unroll
    for (int it = 0; it < 2; ++it) {
        int tl = s_tl + it * 32;
        const size_t base = hbase + (size_t)(t0 + tl) * 64 + s_c;
        v8h sk = *(const v8h*)&skip[base];
        v8h pv = *(const v8h*)&P1[tl * ST + s_c];
        v8h sn;
        #pragma unroll
        for (int r = 0; r < 8; ++r)
            sn[r] = (_Float16)((float)sk[r] + (float)pv[r]);
        *(v8h*)&skip[base] = sn;
    }
#undef STAGE
#undef MFMA_TAP
#undef WOFF
#undef RSOFF
}

// ---------------------------------------------------------------------------
// k_out: out[b][t] = ow2 @ relu(ow1 @ relu(skip[b][t][:]) + ob1) + ob2
// ---------------------------------------------------------------------------
__global__ __launch_bounds__(256) void k_out(const _Float16* __restrict__ skip,
                                             const float* __restrict__ ow1,
                                             const float* __restrict__ ob1,
                                             const float* __restrict__ ow2,
                                             const float* __restrict__ ob2,
                                             float* __restrict__ out)
{
    const int blk = xcd_swizzle(blockIdx.x, Tn / 256);
    const int t  = blk * 256 + threadIdx.x;
    const int bb = blockIdx.y;
    const _Float16* sp = skip + ((size_t)bb * Tn + t) * 64;
    float y[64];
    #pragma unroll
    for (int i = 0; i < 8; ++i) {
        v8h v = *(const v8h*)&sp[i * 8];
        #pragma unroll
        for (int j = 0; j < 8; ++j) y[i * 8 + j] = fmaxf((float)v[j], 0.f);
    }
    float o = ob2[0];
    for (int co = 0; co < 64; ++co) {          // weights uniform -> s_loads
        float a0 = ob1[co], a1 = 0.f;
        #pragma unroll
        for (int ci = 0; ci < 64; ci += 2) {
            a0 = fmaf(ow1[co * 64 + ci],     y[ci],     a0);
            a1 = fmaf(ow1[co * 64 + ci + 1], y[ci + 1], a1);
        }
        o = fmaf(ow2[co], fmaxf(a0 + a1, 0.f), o);
    }
    out[(size_t)bb * Tn + t] = o;
}

// ---------------------------------------------------------------------------
extern "C" void kernel_launch(void* const* d_in, const int* in_sizes, int n_in,
                              void* d_out, int out_size, void* d_ws, size_t ws_size,
                              hipStream_t stream)
{
    const float* x    = (const float*)d_in[0];
    const float* w_in = (const float*)d_in[1];
    const float* b_in = (const float*)d_in[2];
    const float* fw   = (const float*)d_in[3];
    const float* fb   = (const float*)d_in[4];
    const float* gw   = (const float*)d_in[5];
    const float* gb   = (const float*)d_in[6];
    const float* rw   = (const float*)d_in[7];
    const float* rb   = (const float*)d_in[8];
    const float* sw   = (const float*)d_in[9];
    const float* sb   = (const float*)d_in[10];
    const float* ow1  = (const float*)d_in[11];
    const float* ob1  = (const float*)d_in[12];
    const float* ow2  = (const float*)d_in[13];
    const float* ob2  = (const float*)d_in[14];
    float* out = (float*)d_out;

    const size_t n = (size_t)Bn * Tn * 64;
    _Float16* hA    = (_Float16*)d_ws;
    _Float16* hB    = hA + n;
    _Float16* skip  = hB + n;
    _Float16* wfg16 = skip + n;
    _Float16* rs16  = wfg16 + (size_t)Ln * 24576;

    dim3 blk(256);
    k_prep<<<dim3((Ln * 24576 + Ln * 8192 + 255) / 256), blk, 0, stream>>>(
        fw, gw, rw, sw, wfg16, rs16);
    k_input<<<dim3(Tn / 256, Bn), blk, 0, stream>>>(x, w_in, b_in, hA);

    const _Float16* cur = hA;
    _Float16* nxt = hB;
    // layers 0-5: three fused pairs (d = 1, 4, 16)
    for (int l = 0; l < 6; l += 2) {
        const int d = 1 << l;
        k_pair<<<dim3(Tn / 64, Bn), blk, 0, stream>>>(
            cur, nxt, skip,
            wfg16 + (size_t)l * 24576,       rs16 + (size_t)l * 8192,
            wfg16 + (size_t)(l + 1) * 24576, rs16 + (size_t)(l + 1) * 8192,
            fb + l * Cn, gb + l * Cn, rb + l * Cn, sb + l * Cn,
            fb + (l + 1) * Cn, gb + (l + 1) * Cn, rb + (l + 1) * Cn, sb + (l + 1) * Cn,
            d, (l == 0) ? 0.f : 1.f);          // scale=0 absorbs 0xAA ws poison
        const _Float16* tmp = nxt; nxt = (_Float16*)cur; cur = tmp;
    }
    // layers 6-9: single-layer kernels (d = 64..512); layer 9 skips hout
    for (int l = 6; l < Ln; ++l) {
        const int d = 1 << l;
        k_layer<<<dim3(Tn / 64, Bn), blk, 0, stream>>>(
            cur, nxt, skip,
            wfg16 + (size_t)l * 24576, rs16 + (size_t)l * 8192,
            fb + l * Cn, gb + l * Cn, rb + l * Cn, sb + l * Cn,
            d, (l == Ln - 1) ? 0 : 1);
        const _Float16* tmp = nxt; nxt = (_Float16*)cur; cur = tmp;
    }

    k_out<<<dim3(Tn / 256, Bn), blk, 0, stream>>>(skip, ow1, ob1, ow2, ob2, out);
}